// Round 1
// baseline (56.945 us; speedup 1.0000x reference)
//
#include <hip/hip_runtime.h>

#define IMH 512
#define IMW 512
#define BATCH 8
#define NTOK 20480
#define NC 4096
#define NF 16384
#define ED 128

// ---------------- Kernel 1: Sobel edge map + 4x4 average pool (float64) ----
// grid (8,8,8): 64x64 pixel tile per block, 256 threads -> 16x16 pooled cells
__global__ __launch_bounds__(256) void edge_kernel(const float* __restrict__ x,
                                                   double* __restrict__ edges) {
    int b = blockIdx.z;
    int ty0 = blockIdx.y * 64;
    int tx0 = blockIdx.x * 64;
    __shared__ float sm[66][68];
    const float* img = x + (size_t)b * (IMH * IMW);
    for (int idx = threadIdx.x; idx < 66 * 66; idx += 256) {
        int r = idx / 66, c = idx - r * 66;
        int gy = ty0 - 1 + r, gx = tx0 - 1 + c;
        float v = 0.f;
        if (gy >= 0 && gy < IMH && gx >= 0 && gx < IMW) v = img[gy * IMW + gx];
        sm[r][c] = v;
    }
    __syncthreads();
    int t = threadIdx.x;
    int cy = t >> 4, cx = t & 15;
    double acc = 0.0;
    #pragma unroll
    for (int dy = 0; dy < 4; ++dy) {
        int py = cy * 4 + dy + 1;
        #pragma unroll
        for (int dx = 0; dx < 4; ++dx) {
            int px = cx * 4 + dx + 1;
            double a00 = (double)sm[py - 1][px - 1];
            double a01 = (double)sm[py - 1][px];
            double a02 = (double)sm[py - 1][px + 1];
            double a10 = (double)sm[py][px - 1];
            double a12 = (double)sm[py][px + 1];
            double a20 = (double)sm[py + 1][px - 1];
            double a21 = (double)sm[py + 1][px];
            double a22 = (double)sm[py + 1][px + 1];
            double sx = (a02 + 2.0 * a12 + a22) - (a00 + 2.0 * a10 + a20);
            double sy = (a20 + 2.0 * a21 + a22) - (a00 + 2.0 * a01 + a02);
            acc += sqrt(sx * sx + sy * sy);
        }
    }
    int gy = (ty0 >> 2) + cy;
    int gx = (tx0 >> 2) + cx;
    edges[((size_t)b << 14) + gy * 128 + gx] = acc * (1.0 / 16.0);
}

// ---------------- Kernel 2: per-batch mean, mask, prefix scan --------------
// one block per batch, 1024 threads, 16 elements/thread
__global__ __launch_bounds__(1024) void scan_kernel(const double* __restrict__ edges,
                                                    int* __restrict__ pos,
                                                    int* __restrict__ Karr,
                                                    float* __restrict__ mask_out) {
    int b = blockIdx.x;
    const double* e = edges + ((size_t)b << 14);
    int t = threadIdx.x;
    double v[16];
    double s = 0.0;
    #pragma unroll
    for (int j = 0; j < 16; ++j) { v[j] = e[t * 16 + j]; s += v[j]; }
    __shared__ double red[1024];
    red[t] = s;
    __syncthreads();
    for (int off = 512; off > 0; off >>= 1) {
        if (t < off) red[t] += red[t + off];
        __syncthreads();
    }
    double mean = red[0] * (1.0 / 16384.0);
    int m[16];
    int cnt = 0;
    #pragma unroll
    for (int j = 0; j < 16; ++j) { m[j] = (v[j] > mean) ? 1 : 0; cnt += m[j]; }
    __shared__ int sc[1024];
    sc[t] = cnt;
    __syncthreads();
    for (int off = 1; off < 1024; off <<= 1) {
        int add = (t >= off) ? sc[t - off] : 0;
        __syncthreads();
        sc[t] += add;
        __syncthreads();
    }
    int excl = sc[t] - cnt;       // exclusive prefix of selected before this thread
    int K = sc[1023];
    int run = excl;
    #pragma unroll
    for (int j = 0; j < 16; ++j) {
        int i = t * 16 + j;
        mask_out[((size_t)b << 14) + i] = m[j] ? 1.0f : 0.0f;
        pos[((size_t)b << 14) + i] = m[j] ? run : -1;
        run += m[j];
    }
    if (t == 0) Karr[b] = K;
}

// ---------------- Kernel 3: coarse patch embed -----------------------------
// grid (512, 8), 128 threads; 8 coarse patches per block (same patch row)
__global__ __launch_bounds__(128) void coarse_kernel(const float* __restrict__ x,
                                                     const float* __restrict__ wc,
                                                     const float* __restrict__ bc,
                                                     const float* __restrict__ temb,
                                                     float* __restrict__ out) {
    int b = blockIdx.y;
    int p0 = blockIdx.x * 8;
    int hp = p0 >> 6;
    int wp0 = p0 & 63;
    int d = threadIdx.x;
    float wcol[64];
    #pragma unroll
    for (int k = 0; k < 64; ++k) wcol[k] = wc[k * ED + d];
    __shared__ float sm[8][64];
    const float* img = x + ((size_t)b * IMH + hp * 8) * IMW + wp0 * 8;
    #pragma unroll
    for (int idx = d; idx < 512; idx += 128) {
        int r = idx >> 6, c = idx & 63;
        sm[r][c] = img[r * IMW + c];
    }
    __syncthreads();
    float base = bc[d] + temb[d];
    #pragma unroll
    for (int p = 0; p < 8; ++p) {
        float acc = base;
        #pragma unroll
        for (int k = 0; k < 64; ++k) {
            acc += sm[k >> 3][p * 8 + (k & 7)] * wcol[k];
        }
        out[((size_t)b * NTOK + (p0 + p)) * ED + d] = acc;
    }
}

// ---------------- Kernel 4: fine patch embed + compact scatter + fill ------
// grid (1024, 8), 128 threads; 16 fine patches per block (same patch row)
__global__ __launch_bounds__(128) void fine_kernel(const float* __restrict__ x,
                                                   const float* __restrict__ wf,
                                                   const float* __restrict__ bf,
                                                   const float* __restrict__ temb,
                                                   const int* __restrict__ pos,
                                                   const int* __restrict__ Karr,
                                                   float* __restrict__ out) {
    int b = blockIdx.y;
    int i0 = blockIdx.x * 16;
    int hf = i0 >> 7;
    int wf0 = i0 & 127;
    int d = threadIdx.x;
    float wcol[16];
    #pragma unroll
    for (int k = 0; k < 16; ++k) wcol[k] = wf[k * ED + d];
    __shared__ float sm[4][64];
    const float* img = x + ((size_t)b * IMH + hf * 4) * IMW + wf0 * 4;
    #pragma unroll
    for (int idx = d; idx < 256; idx += 128) {
        int r = idx >> 6, c = idx & 63;
        sm[r][c] = img[r * IMW + c];
    }
    __syncthreads();
    int K = Karr[b];
    float fill = temb[ED + d];
    float base = bf[d] + fill;
    float* tok = out + ((size_t)b * NTOK + NC) * ED;
    #pragma unroll
    for (int p = 0; p < 16; ++p) {
        int i = i0 + p;
        int ps = pos[((size_t)b << 14) + i];
        if (ps >= 0) {
            float acc = base;
            #pragma unroll
            for (int k = 0; k < 16; ++k) {
                acc += sm[k >> 2][p * 4 + (k & 3)] * wcol[k];
            }
            tok[(size_t)ps * ED + d] = acc;
        }
        if (i >= K) {
            tok[(size_t)i * ED + d] = fill;
        }
    }
}

extern "C" void kernel_launch(void* const* d_in, const int* in_sizes, int n_in,
                              void* d_out, int out_size, void* d_ws, size_t ws_size,
                              hipStream_t stream) {
    const float* x    = (const float*)d_in[0];
    const float* wc   = (const float*)d_in[1];
    const float* bc   = (const float*)d_in[2];
    const float* wfp  = (const float*)d_in[3];
    const float* bfp  = (const float*)d_in[4];
    const float* temb = (const float*)d_in[5];
    float* out = (float*)d_out;

    double* edges = (double*)d_ws;                                       // 8*16384*8 = 1 MiB
    int* pos  = (int*)((char*)d_ws + (size_t)BATCH * NF * sizeof(double)); // 512 KiB
    int* Karr = (int*)((char*)d_ws + (size_t)BATCH * NF * (sizeof(double) + sizeof(int)));

    float* mask_out = out + (size_t)BATCH * NTOK * ED;

    edge_kernel<<<dim3(8, 8, 8), 256, 0, stream>>>(x, edges);
    scan_kernel<<<dim3(BATCH), 1024, 0, stream>>>(edges, pos, Karr, mask_out);
    coarse_kernel<<<dim3(512, BATCH), 128, 0, stream>>>(x, wc, bc, temb, out);
    fine_kernel<<<dim3(1024, BATCH), 128, 0, stream>>>(x, wfp, bfp, temb, pos, Karr, out);
}